// Round 3
// baseline (159.729 us; speedup 1.0000x reference)
//
#include <hip/hip_runtime.h>
#include <hip/hip_bf16.h>

// KPConv v3:
//   prep: x -> bf16  AND  weights -> Wt2[o][c*16+k] bf16 (c-major K, k=15 zeroed)
//   agg3: per point wf[n][c*16+k] = sum_h w(h,k)*x(h,c); wide coalesced x-gather
//         (4 dwordx4/lane, 2 pts/wave in one latency window) + LDS transpose
//         into MFMA B-layout; D stored as packed dwordx2.
//   gemm3: out = wf[50048,1024] x Wt2^T, 64x128 tile, BK=64, reg prefetch.

#define NPTS   50000
#define NPAD   50048
#define HNB    32
#define KPTS   15
#define CING   64
#define COUTG  128
#define KDIM2  1024          // c-major: kc = c*16 + k (k=15 slot is exact zero)
#define MSUP   50000
#define INV_EXT 13.888889f

typedef __attribute__((ext_vector_type(8))) short bf16x8;
typedef __attribute__((ext_vector_type(4))) float f32x4;

static __device__ __forceinline__ unsigned short f2bf(float f) {
    unsigned int u = __float_as_uint(f);
    u += 0x7FFFu + ((u >> 16) & 1u);
    return (unsigned short)(u >> 16);
}

// ---------------- prep: x->bf16 (blocks 0..1562) + Wt2 (blocks 1563..2074) ----
#define XBLKS 1563
__global__ __launch_bounds__(256) void kpconv_prep(
    const float* __restrict__ x, const float* __restrict__ wgt,
    unsigned short* __restrict__ xb, unsigned short* __restrict__ Wt2)
{
    int b = blockIdx.x;
    if (b < XBLKS) {
        int i = (b * 256 + threadIdx.x) * 8;
        if (i < MSUP * CING) {
            float4 a = *(const float4*)(x + i);
            float4 c = *(const float4*)(x + i + 4);
            unsigned short o[8];
            o[0]=f2bf(a.x); o[1]=f2bf(a.y); o[2]=f2bf(a.z); o[3]=f2bf(a.w);
            o[4]=f2bf(c.x); o[5]=f2bf(c.y); o[6]=f2bf(c.z); o[7]=f2bf(c.w);
            uint4 p;
            p.x = o[0] | (o[1]<<16); p.y = o[2] | (o[3]<<16);
            p.z = o[4] | (o[5]<<16); p.w = o[6] | (o[7]<<16);
            *(uint4*)(xb + i) = p;
        }
    } else {
        int e = (b - XBLKS) * 256 + threadIdx.x;   // 0..131071
        int o = e >> 10, j = e & 1023;
        int c = j >> 4, k = j & 15;
        Wt2[(size_t)o * KDIM2 + j] =
            (k < KPTS) ? f2bf(wgt[((size_t)k * CING + c) * COUTG + o]) : (unsigned short)0;
    }
}

// ---------------- agg3 ----------------
// Block 256 thr = 4 waves; 8 points/block (2 per wave, sequential). Grid 6250.
#define HP 36   // xls pitch (elems): b64 reads conflict-free, writes ~4-way

__global__ __launch_bounds__(256) void kpconv_agg3(
    const float* __restrict__ q_pts, const float* __restrict__ s_pts,
    const int* __restrict__ inds, const unsigned short* __restrict__ xb,
    const float* __restrict__ kpts, unsigned short* __restrict__ wf)
{
    __shared__ float4 nbs[8][HNB];                 // xyz = s-q, w = idx bits
    __shared__ unsigned short xls[4][CING * HP];   // per-wave transpose buffer

    const int tid  = threadIdx.x;
    const int wave = tid >> 6;
    const int lane = tid & 63;
    const int l15  = lane & 15;
    const int quad = lane >> 4;

    // stage all 8 points' neighbor diffs + indices
    {
        int p = tid >> 5, h = tid & 31;
        int n = blockIdx.x * 8 + p;
        int m = inds[n * HNB + h];
        float qx = q_pts[n * 3 + 0];
        float qy = q_pts[n * 3 + 1];
        float qz = q_pts[n * 3 + 2];
        nbs[p][h] = make_float4(s_pts[m * 3 + 0] - qx,
                                s_pts[m * 3 + 1] - qy,
                                s_pts[m * 3 + 2] - qz,
                                __int_as_float(m));
    }
    __syncthreads();

    const bool kvalid = (l15 < KPTS);
    const int  kidx   = kvalid ? l15 : 0;
    const float kx = kpts[kidx * 3 + 0];
    const float ky = kpts[kidx * 3 + 1];
    const float kz = kpts[kidx * 3 + 2];

    const int mch  = lane & 7;    // c-chunk (8 elems each)
    const int hrow = lane >> 3;   // base h row

    // issue both points' gathers in one latency window (8 dwordx4 in flight)
    uint4 g[2][4];
#pragma unroll
    for (int pp = 0; pp < 2; ++pp) {
        int p = wave * 2 + pp;
#pragma unroll
        for (int i = 0; i < 4; ++i) {
            int m = __float_as_int(nbs[p][hrow + 8 * i].w);
            g[pp][i] = *(const uint4*)(xb + ((size_t)m << 6) + mch * 8);
        }
    }

    // A-frags (overlaps load latency): af[pp][j] = w(k=l15, h=quad*8+j)
    bf16x8 af[2];
#pragma unroll
    for (int pp = 0; pp < 2; ++pp) {
        int p = wave * 2 + pp;
#pragma unroll
        for (int j = 0; j < 8; ++j) {
            float4 v = nbs[p][quad * 8 + j];
            float dx = v.x - kx, dy = v.y - ky, dz = v.z - kz;
            float d  = sqrtf(dx * dx + dy * dy + dz * dz);
            float w  = kvalid ? fmaxf(0.f, 1.f - d * INV_EXT) : 0.f;
            af[pp][j] = (short)f2bf(w);
        }
    }

    unsigned short* X = xls[wave];

#pragma unroll
    for (int pp = 0; pp < 2; ++pp) {
        const int n = blockIdx.x * 8 + wave * 2 + pp;

        // transpose-write: element t of g[pp][i] is x[h=hrow+8i][c=8*mch+t]
#pragma unroll
        for (int i = 0; i < 4; ++i) {
            int h  = hrow + 8 * i;
            int cb = mch * 8;
            unsigned int d0 = g[pp][i].x, d1 = g[pp][i].y,
                         d2 = g[pp][i].z, d3 = g[pp][i].w;
            X[(cb + 0) * HP + h] = (unsigned short)(d0);
            X[(cb + 1) * HP + h] = (unsigned short)(d0 >> 16);
            X[(cb + 2) * HP + h] = (unsigned short)(d1);
            X[(cb + 3) * HP + h] = (unsigned short)(d1 >> 16);
            X[(cb + 4) * HP + h] = (unsigned short)(d2);
            X[(cb + 5) * HP + h] = (unsigned short)(d2 >> 16);
            X[(cb + 6) * HP + h] = (unsigned short)(d3);
            X[(cb + 7) * HP + h] = (unsigned short)(d3 >> 16);
        }
        __syncthreads();   // waves symmetric; orders write->read (and prev read->write)

        f32x4 acc[4];
#pragma unroll
        for (int nt = 0; nt < 4; ++nt) acc[nt] = (f32x4){0.f, 0.f, 0.f, 0.f};

#pragma unroll
        for (int nt = 0; nt < 4; ++nt) {
            int c = l15 + 16 * nt;
            bf16x8 bfr;
            ((uint2*)&bfr)[0] = *(const uint2*)&X[c * HP + quad * 8];
            ((uint2*)&bfr)[1] = *(const uint2*)&X[c * HP + quad * 8 + 4];
            acc[nt] = __builtin_amdgcn_mfma_f32_16x16x32_bf16(af[pp], bfr, acc[nt], 0, 0, 0);
        }
        __syncthreads();   // reads done before next pp overwrites X

        // store wf[n][c*16 + k], k = quad*4 + r  (packed 4 bf16 = 8 B)
        const size_t base = (size_t)n * KDIM2;
#pragma unroll
        for (int nt = 0; nt < 4; ++nt) {
            int c = l15 + 16 * nt;
            uint2 pk;
            pk.x = f2bf(acc[nt][0]) | ((unsigned int)f2bf(acc[nt][1]) << 16);
            pk.y = f2bf(acc[nt][2]) | ((unsigned int)f2bf(acc[nt][3]) << 16);
            *(uint2*)(wf + base + c * 16 + quad * 4) = pk;
        }
    }
}

// ---------------- gemm3: 64x128, BK=64, reg prefetch (R2 structure, K=1024) ----
#define GBM 64
#define GBK 64
#define GLP 72

__global__ __launch_bounds__(256) void kpconv_gemm3(
    const unsigned short* __restrict__ A,   // wf [NPAD][1024]
    const unsigned short* __restrict__ Bt,  // Wt2 [128][1024]
    const float* __restrict__ bias,
    float* __restrict__ out)
{
    __shared__ unsigned short As[GBM * GLP];
    __shared__ unsigned short Bs[COUTG * GLP];

    const int tid  = threadIdx.x;
    const int wave = tid >> 6;
    const int lane = tid & 63;
    const int l15  = lane & 15;
    const int quad = lane >> 4;
    const long blockM = (long)blockIdx.x * GBM;

    f32x4 acc[8];
#pragma unroll
    for (int i = 0; i < 8; ++i) acc[i] = (f32x4){0.f, 0.f, 0.f, 0.f};

    const int arow = tid >> 2, acol = (tid & 3) * 16;
    const int brow = tid >> 1, bcol = (tid & 1) * 32;
    const unsigned short* aptr = A + (size_t)(blockM + arow) * KDIM2 + acol;
    const unsigned short* bptr = Bt + (size_t)brow * KDIM2 + bcol;

    uint4 ra0 = *(const uint4*)(aptr);
    uint4 ra1 = *(const uint4*)(aptr + 8);
    uint4 rb0 = *(const uint4*)(bptr);
    uint4 rb1 = *(const uint4*)(bptr + 8);
    uint4 rb2 = *(const uint4*)(bptr + 16);
    uint4 rb3 = *(const uint4*)(bptr + 24);

    for (int kk = 0; kk < KDIM2; kk += GBK) {
        __syncthreads();
        *(uint4*)&As[arow * GLP + acol]      = ra0;
        *(uint4*)&As[arow * GLP + acol + 8]  = ra1;
        *(uint4*)&Bs[brow * GLP + bcol]      = rb0;
        *(uint4*)&Bs[brow * GLP + bcol + 8]  = rb1;
        *(uint4*)&Bs[brow * GLP + bcol + 16] = rb2;
        *(uint4*)&Bs[brow * GLP + bcol + 24] = rb3;
        __syncthreads();

        if (kk + GBK < KDIM2) {
            ra0 = *(const uint4*)(aptr + kk + GBK);
            ra1 = *(const uint4*)(aptr + kk + GBK + 8);
            rb0 = *(const uint4*)(bptr + kk + GBK);
            rb1 = *(const uint4*)(bptr + kk + GBK + 8);
            rb2 = *(const uint4*)(bptr + kk + GBK + 16);
            rb3 = *(const uint4*)(bptr + kk + GBK + 24);
        }

#pragma unroll
        for (int ch = 0; ch < 2; ++ch) {
            bf16x8 afr = *(bf16x8*)&As[(wave * 16 + l15) * GLP + ch * 32 + quad * 8];
#pragma unroll
            for (int nf = 0; nf < 8; ++nf) {
                bf16x8 bfr = *(bf16x8*)&Bs[(nf * 16 + l15) * GLP + ch * 32 + quad * 8];
                acc[nf] = __builtin_amdgcn_mfma_f32_16x16x32_bf16(afr, bfr, acc[nf], 0, 0, 0);
            }
        }
    }

    const long r0 = blockM + wave * 16 + quad * 4;
#pragma unroll
    for (int nf = 0; nf < 8; ++nf) {
        const int col = nf * 16 + l15;
        const float bv = bias[col];
#pragma unroll
        for (int r = 0; r < 4; ++r) {
            long row = r0 + r;
            if (row < NPTS) out[row * COUTG + col] = acc[nf][r] + bv;
        }
    }
}

extern "C" void kernel_launch(void* const* d_in, const int* in_sizes, int n_in,
                              void* d_out, int out_size, void* d_ws, size_t ws_size,
                              hipStream_t stream) {
    const float* q_pts = (const float*)d_in[0];
    const float* s_pts = (const float*)d_in[1];
    const int*   inds  = (const int*)d_in[2];
    const float* x     = (const float*)d_in[3];
    const float* kpts  = (const float*)d_in[4];
    const float* wgt   = (const float*)d_in[5];
    const float* bias  = (const float*)d_in[6];
    float* out = (float*)d_out;

    // ws: wf [NPAD*1024] bf16 | xb [50000*64] bf16 | Wt2 [128*1024] bf16
    unsigned short* wf = (unsigned short*)d_ws;
    unsigned short* xb = wf + (size_t)NPAD * KDIM2;
    unsigned short* Wt2 = xb + (size_t)MSUP * CING;

    kpconv_prep<<<XBLKS + 512, 256, 0, stream>>>(x, wgt, xb, Wt2);
    kpconv_agg3<<<NPTS / 8, 256, 0, stream>>>(q_pts, s_pts, inds, xb, kpts, wf);
    kpconv_gemm3<<<NPAD / GBM, 256, 0, stream>>>(wf, Wt2, bias, out);
}